// Round 5
// baseline (2656.164 us; speedup 1.0000x reference)
//
#include <hip/hip_runtime.h>

typedef _Float16 half8 __attribute__((ext_vector_type(8)));
typedef float f32x4 __attribute__((ext_vector_type(4)));

#define NT 512   // timesteps
#define NB 128   // batch
#define NI 256   // input dim
#define NH 512   // hidden dim
#define FLAG_STRIDE 16  // ints -> 64B per flag, avoid line sharing

// ---------------------------------------------------------------------------
// W (fp32 [N][K]) -> fragment-linear f16 for MFMA B-operand.
// Block b = t_n*KT + t_k; lane l holds 8 elems: n = t_n*16 + (l&15),
// k = t_k*32 + (l>>4)*8 + j. Also zeroes the 8x8 group/slice flags.
// Grid 196*256 = 50176 = 32768 + 16384 + 1024 exactly.
// ---------------------------------------------------------------------------
__global__ void w_transform(const float* __restrict__ Whh,
                            const float* __restrict__ Win,
                            _Float16* __restrict__ Wf_hh,
                            _Float16* __restrict__ Wf_in,
                            int* __restrict__ flags) {
  int tid = blockIdx.x * blockDim.x + threadIdx.x;
  if (tid < 32768) {                    // W_hh: 32 n-tiles * 16 k-tiles
    int l = tid & 63, b = tid >> 6;
    int tk = b & 15, tn = b >> 4;
    int n = tn * 16 + (l & 15);
    int k = tk * 32 + (l >> 4) * 8;
    const float* src = Whh + (size_t)n * NH + k;
    _Float16* dst = Wf_hh + (size_t)tid * 8;
#pragma unroll
    for (int j = 0; j < 8; ++j) dst[j] = (_Float16)src[j];
  } else if (tid < 32768 + 16384) {     // W_in: 32 n-tiles * 8 k-tiles
    int t2 = tid - 32768;
    int l = t2 & 63, b = t2 >> 6;
    int tk = b & 7, tn = b >> 3;
    int n = tn * 16 + (l & 15);
    int k = tk * 32 + (l >> 4) * 8;
    const float* src = Win + (size_t)n * NI + k;
    _Float16* dst = Wf_in + (size_t)t2 * 8;
#pragma unroll
    for (int j = 0; j < 8; ++j) dst[j] = (_Float16)src[j];
  } else {                              // 8 groups * 8 slices * FLAG_STRIDE
    flags[tid - 32768 - 16384] = 0;
  }
}

// ---------------------------------------------------------------------------
// Phase 1: xin = x @ W_in^T  (M=65536, K=256, N=512), fp32 out into d_out.
// (unchanged from the passing baseline)
// ---------------------------------------------------------------------------
__global__ __launch_bounds__(256)
void input_proj(const float* __restrict__ x,
                const _Float16* __restrict__ Wf_in,
                float* __restrict__ xin) {
  int lane = threadIdx.x & 63;
  int wv = threadIdx.x >> 6;
  int m0 = blockIdx.x * 16;
  int c = lane & 15, q = lane >> 4;
  int row = m0 + c;

  f32x4 acc[8];
#pragma unroll
  for (int i = 0; i < 8; ++i) acc[i] = (f32x4){0.f, 0.f, 0.f, 0.f};

#pragma unroll
  for (int kc = 0; kc < 8; ++kc) {
    const float4* ap = (const float4*)(x + (size_t)row * NI + kc * 32 + q * 8);
    float4 a0 = ap[0], a1 = ap[1];
    half8 a;
    a[0] = (_Float16)a0.x; a[1] = (_Float16)a0.y;
    a[2] = (_Float16)a0.z; a[3] = (_Float16)a0.w;
    a[4] = (_Float16)a1.x; a[5] = (_Float16)a1.y;
    a[6] = (_Float16)a1.z; a[7] = (_Float16)a1.w;
#pragma unroll
    for (int nt = 0; nt < 8; ++nt) {
      int tn = wv * 8 + nt;
      const half8* bp =
          (const half8*)(Wf_in + (((size_t)(tn * 8 + kc)) * 64 + lane) * 8);
      acc[nt] = __builtin_amdgcn_mfma_f32_16x16x32_f16(a, *bp, acc[nt], 0, 0, 0);
    }
  }
#pragma unroll
  for (int nt = 0; nt < 8; ++nt) {
    int n = wv * 128 + nt * 16 + c;
#pragma unroll
    for (int r = 0; r < 4; ++r) {
      int m = q * 4 + r;
      xin[(size_t)(m0 + m) * NH + n] = acc[nt][r];
    }
  }
}

// ---------------------------------------------------------------------------
// Phase 2: recurrence. 64 wgs = 8 batch-groups x 8 col-slices (64 cols each),
// 256 threads (4 waves), bfrag[16] = 64 regs/wave (the PROVEN-resident shape).
//
// ZERO LDS. The exchange buffer hbuf is ROW-major f16 [2][NB][NH], so an MFMA
// A-fragment for k-chunk kc is lane (c,q) reading 16 contiguous bytes at
// hbuf[slot][m0+c][kc*32+q*8] -- two relaxed agent-scope u64 atomic loads
// straight into the operand. No LDS bounce, no refill phase, one barrier/step.
//
// Flag protocol (proven baseline semantics):
//  * publisher: epilogue emits 4 relaxed agent u16 stores (its col, 4 rows)
//    into slot t&1; __syncthreads() (per-wave vmcnt(0) drain before s_barrier
//    makes every wave's publishes AND its slot reads LLC-complete); tid0
//    stores flag := t+1 (relaxed agent). dout stores issue AFTER the flag --
//    their acks are off the critical path.
//  * consumer at step t: spin until min over the group's 8 flags >= t, then
//    load slot (t-1)&1 A-fragments directly.
//  * slot-reuse: flag=t from partner => its slot-(t&1) reads of step t-1 are
//    drained (same barrier covers loads); we write slot t&1 only after
//    observing all 8 flags >= t. Order: reads < flag < observe < overwrite.
//  * t=0: A-fragments converted from h0 (f32) directly; no exchange needed.
// ---------------------------------------------------------------------------
__global__ __launch_bounds__(256, 1)
void recurrence(float* __restrict__ dout,          // xin in-place -> h, + final
                const float* __restrict__ h0,
                const _Float16* __restrict__ Wf,   // fragment-linear W_hh
                unsigned long long* __restrict__ hbuf64,  // [2][NB][NH] f16 row-major
                int* __restrict__ flags) {
  int g = blockIdx.x >> 3, s = blockIdx.x & 7;
  int tid = threadIdx.x, lane = tid & 63, wv = tid >> 6;  // 4 waves
  int c = lane & 15, q = lane >> 4;
  int m0 = g * 16;                       // batch row base
  int ncol = s * 64 + wv * 16 + c;       // global col this thread owns

  // resident B-fragments: this wave's 16-col n-tile, all 16 k-chunks (64 regs)
  int nt_global = s * 4 + wv;
  half8 bfrag[16];
#pragma unroll
  for (int kc = 0; kc < 16; ++kc)
    bfrag[kc] =
        *(const half8*)(Wf + (((size_t)(nt_global * 16 + kc)) * 64 + lane) * 8);

  // fp32 master state: this thread's 4 rows x 1 col (C-fragment layout)
  float h32r[4];
#pragma unroll
  for (int r = 0; r < 4; ++r)
    h32r[r] = h0[(size_t)(m0 + q * 4 + r) * NH + ncol];

  unsigned short* hb16 = (unsigned short*)hbuf64;
  int* fbase = flags + g * 8 * FLAG_STRIDE;
  int* myflag = fbase + s * FLAG_STRIDE;

#pragma unroll 1
  for (int t = 0; t < NT; ++t) {
    // xin: 4 scattered dwords, consumed in the epilogue (latency hidden)
    const float* xp = dout + ((size_t)t * NB + m0) * NH;
    float xv[4];
#pragma unroll
    for (int r = 0; r < 4; ++r) xv[r] = xp[(size_t)(q * 4 + r) * NH + ncol];

    // --- A-fragments: rows m0+c, k = kc*32 + q*8 .. +7 ---
    half8 afrag[16];
    if (t == 0) {
      const float* hp = h0 + (size_t)(m0 + c) * NH + q * 8;
#pragma unroll
      for (int kc = 0; kc < 16; ++kc) {
        float4 a0 = ((const float4*)(hp + kc * 32))[0];
        float4 a1 = ((const float4*)(hp + kc * 32))[1];
        half8 a;
        a[0] = (_Float16)a0.x; a[1] = (_Float16)a0.y;
        a[2] = (_Float16)a0.z; a[3] = (_Float16)a0.w;
        a[4] = (_Float16)a1.x; a[5] = (_Float16)a1.y;
        a[6] = (_Float16)a1.z; a[7] = (_Float16)a1.w;
        afrag[kc] = a;
      }
    } else {
      // spin: min over the group's 8 flags (own is trivially satisfied)
      for (;;) {
        int mn = 0x7fffffff;
#pragma unroll
        for (int j = 0; j < 8; ++j) {
          int f = __hip_atomic_load(fbase + j * FLAG_STRIDE, __ATOMIC_RELAXED,
                                    __HIP_MEMORY_SCOPE_AGENT);
          mn = min(mn, f);
        }
        if (mn >= t) break;
      }
      // 32 pipelined u64 agent-atomic loads -> 16 A-fragments
      const unsigned long long* src =
          hbuf64 + ((size_t)((t - 1) & 1) * NB + m0 + c) * (NH / 4) + q * 2;
#pragma unroll
      for (int kc = 0; kc < 16; ++kc) {
        union { unsigned long long u[2]; half8 h; } cv;
        cv.u[0] = __hip_atomic_load(src + kc * 8, __ATOMIC_RELAXED,
                                    __HIP_MEMORY_SCOPE_AGENT);
        cv.u[1] = __hip_atomic_load(src + kc * 8 + 1, __ATOMIC_RELAXED,
                                    __HIP_MEMORY_SCOPE_AGENT);
        afrag[kc] = cv.h;
      }
    }

    // --- P = h @ Wslice^T, K=512; two acc chains ---
    f32x4 acc0 = (f32x4){0.f, 0.f, 0.f, 0.f};
    f32x4 acc1 = (f32x4){0.f, 0.f, 0.f, 0.f};
#pragma unroll
    for (int kc = 0; kc < 16; kc += 2) {
      acc0 = __builtin_amdgcn_mfma_f32_16x16x32_f16(afrag[kc], bfrag[kc], acc0, 0, 0, 0);
      acc1 = __builtin_amdgcn_mfma_f32_16x16x32_f16(afrag[kc + 1], bfrag[kc + 1], acc1, 0, 0, 0);
    }

    // --- epilogue: h_new = relu(0.8 h + 0.2 (xin + P)) ---
    bool last = (t == NT - 1);
    int slotw = t & 1;
#pragma unroll
    for (int r = 0; r < 4; ++r) {
      float hn = 0.8f * h32r[r] + 0.2f * (xv[r] + acc0[r] + acc1[r]);
      hn = fmaxf(hn, 0.f);
      h32r[r] = hn;
      if (!last) {
        union { _Float16 h; unsigned short u; } cv;
        cv.h = (_Float16)hn;
        __hip_atomic_store(
            hb16 + ((size_t)slotw * NB + m0 + q * 4 + r) * NH + ncol, cv.u,
            __ATOMIC_RELAXED, __HIP_MEMORY_SCOPE_AGENT);
      }
    }

    if (!last) {
      __syncthreads();  // per-wave vmcnt(0) drain: publishes + slot reads done
      if (tid == 0)
        __hip_atomic_store(myflag, t + 1, __ATOMIC_RELAXED,
                           __HIP_MEMORY_SCOPE_AGENT);
    }

    // dout stores AFTER the flag: off the critical path
#pragma unroll
    for (int r = 0; r < 4; ++r) {
      int m = q * 4 + r;
      dout[((size_t)t * NB + m0 + m) * NH + ncol] = h32r[r];
      if (last)
        dout[(size_t)NT * NB * NH + (size_t)(m0 + m) * NH + ncol] = h32r[r];
    }
  }
}

// ---------------------------------------------------------------------------
extern "C" void kernel_launch(void* const* d_in, const int* in_sizes, int n_in,
                              void* d_out, int out_size, void* d_ws,
                              size_t ws_size, hipStream_t stream) {
  const float* x      = (const float*)d_in[0];   // [512][128][256]
  const float* hidden = (const float*)d_in[1];   // [128][512]
  const float* W_in   = (const float*)d_in[2];   // [512][256]
  const float* W_hh   = (const float*)d_in[3];   // [512][512]
  float* out = (float*)d_out;

  // ws layout (776KB): Wf_hh 512KB | Wf_in 256KB (aliased by hbuf after
  // input_proj; flag-gated so no zero-init needed) | flags 4KB
  _Float16* Wf_hh = (_Float16*)d_ws;
  _Float16* Wf_in = Wf_hh + (size_t)NH * NH;
  unsigned long long* hbuf = (unsigned long long*)Wf_in;  // alias, stream-ordered
  int* flags = (int*)((char*)d_ws + (size_t)NH * NH * 2 + (size_t)NH * NI * 2);

  w_transform<<<196, 256, 0, stream>>>(W_hh, W_in, Wf_hh, Wf_in, flags);
  input_proj<<<(NT * NB) / 16, 256, 0, stream>>>(x, Wf_in, out);

  void* args[] = {(void*)&out, (void*)&hidden, (void*)&Wf_hh, (void*)&hbuf,
                  (void*)&flags};
  hipLaunchCooperativeKernel((void*)recurrence, dim3(64), dim3(256), args, 0,
                             stream);
}

// Round 6
// 2138.203 us; speedup vs baseline: 1.2422x; 1.2422x over previous
//
#include <hip/hip_runtime.h>

typedef _Float16 half8 __attribute__((ext_vector_type(8)));
typedef float f32x4 __attribute__((ext_vector_type(4)));

#define NT 512   // timesteps
#define NB 128   // batch
#define NI 256   // input dim
#define NH 512   // hidden dim
#define FLAG_STRIDE 4   // ints -> 16B per flag; LLC-only access, no caching

// ---------------------------------------------------------------------------
// W (fp32 [N][K]) -> fragment-linear f16 for MFMA B-operand.
// Block b = t_n*KT + t_k; lane l holds 8 elems: n = t_n*16 + (l&15),
// k = t_k*32 + (l>>4)*8 + j. Also zeroes the 8 groups x 32 wave-flags.
// Grid 196*256 = 50176 = 32768 + 16384 + 1024 exactly.
// ---------------------------------------------------------------------------
__global__ void w_transform(const float* __restrict__ Whh,
                            const float* __restrict__ Win,
                            _Float16* __restrict__ Wf_hh,
                            _Float16* __restrict__ Wf_in,
                            int* __restrict__ flags) {
  int tid = blockIdx.x * blockDim.x + threadIdx.x;
  if (tid < 32768) {                    // W_hh: 32 n-tiles * 16 k-tiles
    int l = tid & 63, b = tid >> 6;
    int tk = b & 15, tn = b >> 4;
    int n = tn * 16 + (l & 15);
    int k = tk * 32 + (l >> 4) * 8;
    const float* src = Whh + (size_t)n * NH + k;
    _Float16* dst = Wf_hh + (size_t)tid * 8;
#pragma unroll
    for (int j = 0; j < 8; ++j) dst[j] = (_Float16)src[j];
  } else if (tid < 32768 + 16384) {     // W_in: 32 n-tiles * 8 k-tiles
    int t2 = tid - 32768;
    int l = t2 & 63, b = t2 >> 6;
    int tk = b & 7, tn = b >> 3;
    int n = tn * 16 + (l & 15);
    int k = tk * 32 + (l >> 4) * 8;
    const float* src = Win + (size_t)n * NI + k;
    _Float16* dst = Wf_in + (size_t)t2 * 8;
#pragma unroll
    for (int j = 0; j < 8; ++j) dst[j] = (_Float16)src[j];
  } else {                              // 8 groups * 32 waves * FLAG_STRIDE
    flags[tid - 32768 - 16384] = 0;
  }
}

// ---------------------------------------------------------------------------
// Phase 1: xin = x @ W_in^T  (M=65536, K=256, N=512), fp32 out into d_out.
// (unchanged from the passing baseline)
// ---------------------------------------------------------------------------
__global__ __launch_bounds__(256)
void input_proj(const float* __restrict__ x,
                const _Float16* __restrict__ Wf_in,
                float* __restrict__ xin) {
  int lane = threadIdx.x & 63;
  int wv = threadIdx.x >> 6;
  int m0 = blockIdx.x * 16;
  int c = lane & 15, q = lane >> 4;
  int row = m0 + c;

  f32x4 acc[8];
#pragma unroll
  for (int i = 0; i < 8; ++i) acc[i] = (f32x4){0.f, 0.f, 0.f, 0.f};

#pragma unroll
  for (int kc = 0; kc < 8; ++kc) {
    const float4* ap = (const float4*)(x + (size_t)row * NI + kc * 32 + q * 8);
    float4 a0 = ap[0], a1 = ap[1];
    half8 a;
    a[0] = (_Float16)a0.x; a[1] = (_Float16)a0.y;
    a[2] = (_Float16)a0.z; a[3] = (_Float16)a0.w;
    a[4] = (_Float16)a1.x; a[5] = (_Float16)a1.y;
    a[6] = (_Float16)a1.z; a[7] = (_Float16)a1.w;
#pragma unroll
    for (int nt = 0; nt < 8; ++nt) {
      int tn = wv * 8 + nt;
      const half8* bp =
          (const half8*)(Wf_in + (((size_t)(tn * 8 + kc)) * 64 + lane) * 8);
      acc[nt] = __builtin_amdgcn_mfma_f32_16x16x32_f16(a, *bp, acc[nt], 0, 0, 0);
    }
  }
#pragma unroll
  for (int nt = 0; nt < 8; ++nt) {
    int n = wv * 128 + nt * 16 + c;
#pragma unroll
    for (int r = 0; r < 4; ++r) {
      int m = q * 4 + r;
      xin[(size_t)(m0 + m) * NH + n] = acc[nt][r];
    }
  }
}

// ---------------------------------------------------------------------------
// Phase 2: recurrence. 64 wgs = 8 batch-groups x 8 col-slices (64 cols each),
// 256 threads (4 waves), bfrag[16]/wave resident (round-0's proven shape),
// h_sh[16][520] LDS staging for the MFMA A operand (round-0's proven shape).
//
// Per-step chain, shortened from round-0's 4 barriers to ONE:
//  * hbuf col-major f16 [2][NH][NB]: each thread's 4 epilogue values (4 rows
//    x 1 col) = ONE coalesced u64 relaxed agent store. No LDS bounce, no
//    sync(a).
//  * per-WAVE flags (8 slices x 4 waves = 32/group): after its publish
//    store, each wave waits s_waitcnt vmcnt(0) (only the publish is
//    outstanding at that point) and lane0 stores its wave-flag. No sync(b)
//    barrier. The asm "memory" clobber pins the flag store after the wait;
//    hardware orders the publish ack before the flag issues.
//  * EVERY wave spins: lanes 0..31 each watch one of the group's 32 flags;
//    wave proceeds on reconvergence. No sync(c).
//  * refill: 8 u64 loads/thread from the just-published slot -> transpose
//    into h_sh. dout h-stores issue AFTER the refill loads (compiler emits
//    a counted vmcnt for the loads; store acks drain at sync(d), overlapped).
//  * sync(d): the single barrier -- h_sh ready for next step's ds_reads.
// Slot reuse is safe by the same transitive argument as the baseline:
// my slot-t reads drain at my sync(d)(t) < my flag(t+2); partner overwrites
// slot t&1 at its step t+2 only after observing all flags >= t+2.
// ---------------------------------------------------------------------------
__global__ __launch_bounds__(256, 1)
void recurrence(float* __restrict__ dout,          // xin in-place -> h, + final
                const float* __restrict__ h0,
                const _Float16* __restrict__ Wf,   // fragment-linear W_hh
                unsigned long long* __restrict__ hbuf64,  // [2][NH][NB] f16
                int* __restrict__ flags) {
  __shared__ _Float16 h_sh[16][520];   // full h rows (A source), 16B rows

  int g = blockIdx.x >> 3, s = blockIdx.x & 7;
  int tid = threadIdx.x, lane = tid & 63, wv = tid >> 6;  // 4 waves
  int c = lane & 15, q = lane >> 4;
  int m0 = g * 16;                       // batch row base
  int ncol = s * 64 + wv * 16 + c;       // global col this thread owns

  // resident B-fragments: this wave's 16-col n-tile, all 16 k-chunks (64 regs)
  int nt_global = s * 4 + wv;
  half8 bfrag[16];
#pragma unroll
  for (int kc = 0; kc < 16; ++kc)
    bfrag[kc] =
        *(const half8*)(Wf + (((size_t)(nt_global * 16 + kc)) * 64 + lane) * 8);

  // fp32 master state: this thread's 4 rows x 1 col (C-fragment layout)
  float h32r[4];
#pragma unroll
  for (int r = 0; r < 4; ++r)
    h32r[r] = h0[(size_t)(m0 + q * 4 + r) * NH + ncol];

  // init h_sh from h0
  for (int i = tid; i < 16 * 512; i += 256)
    h_sh[i >> 9][i & 511] = (_Float16)h0[(size_t)(m0 + (i >> 9)) * NH + (i & 511)];
  __syncthreads();

  unsigned short* hsb = (unsigned short*)&h_sh[0][0];
  int* fbase = flags + g * 32 * FLAG_STRIDE;
  int* myflag = fbase + (s * 4 + wv) * FLAG_STRIDE;

#pragma unroll 1
  for (int t = 0; t < NT; ++t) {
    // xin: 4 scattered dwords, consumed in the epilogue (latency hidden)
    const float* xp = dout + ((size_t)t * NB + m0) * NH;
    float xv[4];
#pragma unroll
    for (int r = 0; r < 4; ++r) xv[r] = xp[(size_t)(q * 4 + r) * NH + ncol];

    // --- P = h @ Wslice^T, K=512; two acc chains ---
    f32x4 acc0 = (f32x4){0.f, 0.f, 0.f, 0.f};
    f32x4 acc1 = (f32x4){0.f, 0.f, 0.f, 0.f};
#pragma unroll
    for (int kc = 0; kc < 16; kc += 2) {
      half8 a0 = *(const half8*)&h_sh[c][kc * 32 + q * 8];
      half8 a1 = *(const half8*)&h_sh[c][(kc + 1) * 32 + q * 8];
      acc0 = __builtin_amdgcn_mfma_f32_16x16x32_f16(a0, bfrag[kc], acc0, 0, 0, 0);
      acc1 = __builtin_amdgcn_mfma_f32_16x16x32_f16(a1, bfrag[kc + 1], acc1, 0, 0, 0);
    }

    // --- epilogue: h_new = relu(0.8 h + 0.2 (xin + P)) ---
    bool last = (t == NT - 1);
    unsigned long long pk = 0;
#pragma unroll
    for (int r = 0; r < 4; ++r) {
      float hn = 0.8f * h32r[r] + 0.2f * (xv[r] + acc0[r] + acc1[r]);
      hn = fmaxf(hn, 0.f);
      h32r[r] = hn;
      union { _Float16 h; unsigned short u; } cv;
      cv.h = (_Float16)hn;
      pk |= (unsigned long long)cv.u << (16 * r);
    }

    if (!last) {
      // publish: one u64 per thread, col-major slot t&1
      __hip_atomic_store(
          hbuf64 + ((size_t)(t & 1) * NH + ncol) * 32 + (m0 >> 2) + q, pk,
          __ATOMIC_RELAXED, __HIP_MEMORY_SCOPE_AGENT);
      // wave-local drain of the publish store, then wave-flag
      asm volatile("s_waitcnt vmcnt(0)" ::: "memory");
      if (lane == 0)
        __hip_atomic_store(myflag, t + 1, __ATOMIC_RELAXED,
                           __HIP_MEMORY_SCOPE_AGENT);
      // spin: lanes 0..31 each watch one of the group's 32 wave-flags
      if (lane < 32) {
        while (__hip_atomic_load(fbase + lane * FLAG_STRIDE, __ATOMIC_RELAXED,
                                 __HIP_MEMORY_SCOPE_AGENT) < t + 1) {
        }
      }
      // refill: 8 u64 loads/thread from slot t&1 (col-major)
      const unsigned long long* src =
          hbuf64 + (size_t)(t & 1) * NH * 32 + (m0 >> 2);
      unsigned long long rv[8];
#pragma unroll
      for (int j = 0; j < 8; ++j) {
        int k = tid + j * 256;           // col = k>>2, row-quad = k&3
        rv[j] = __hip_atomic_load(src + (size_t)(k >> 2) * 32 + (k & 3),
                                  __ATOMIC_RELAXED, __HIP_MEMORY_SCOPE_AGENT);
      }
      // dout h-stores now: acks overlap the LDS writes, drain at sync(d)
#pragma unroll
      for (int r = 0; r < 4; ++r)
        dout[((size_t)t * NB + m0 + q * 4 + r) * NH + ncol] = h32r[r];
      // transpose into h_sh
#pragma unroll
      for (int j = 0; j < 8; ++j) {
        int k = tid + j * 256, col = k >> 2, rq = k & 3;
#pragma unroll
        for (int i = 0; i < 4; ++i)
          hsb[(size_t)(rq * 4 + i) * 520 + col] =
              (unsigned short)(rv[j] >> (16 * i));
      }
      __syncthreads();  // (d) h_sh ready; refill loads + dout stores drained
    } else {
#pragma unroll
      for (int r = 0; r < 4; ++r) {
        int m = q * 4 + r;
        dout[((size_t)t * NB + m0 + m) * NH + ncol] = h32r[r];
        dout[(size_t)NT * NB * NH + (size_t)(m0 + m) * NH + ncol] = h32r[r];
      }
    }
  }
}

// ---------------------------------------------------------------------------
extern "C" void kernel_launch(void* const* d_in, const int* in_sizes, int n_in,
                              void* d_out, int out_size, void* d_ws,
                              size_t ws_size, hipStream_t stream) {
  const float* x      = (const float*)d_in[0];   // [512][128][256]
  const float* hidden = (const float*)d_in[1];   // [128][512]
  const float* W_in   = (const float*)d_in[2];   // [512][256]
  const float* W_hh   = (const float*)d_in[3];   // [512][512]
  float* out = (float*)d_out;

  // ws layout (772KB, identical to the passing baseline):
  //   Wf_hh 512KB | Wf_in 256KB (aliased by hbuf after input_proj; flag-gated
  //   so no zero-init needed) | flags 4KB
  _Float16* Wf_hh = (_Float16*)d_ws;
  _Float16* Wf_in = Wf_hh + (size_t)NH * NH;
  unsigned long long* hbuf = (unsigned long long*)Wf_in;  // alias, stream-ordered
  int* flags = (int*)((char*)d_ws + (size_t)NH * NH * 2 + (size_t)NH * NI * 2);

  w_transform<<<196, 256, 0, stream>>>(W_hh, W_in, Wf_hh, Wf_in, flags);
  input_proj<<<(NT * NB) / 16, 256, 0, stream>>>(x, Wf_in, out);

  void* args[] = {(void*)&out, (void*)&hidden, (void*)&Wf_hh, (void*)&hbuf,
                  (void*)&flags};
  hipLaunchCooperativeKernel((void*)recurrence, dim3(64), dim3(256), args, 0,
                             stream);
}

// Round 7
// 1807.504 us; speedup vs baseline: 1.4695x; 1.1830x over previous
//
#include <hip/hip_runtime.h>

typedef _Float16 half8 __attribute__((ext_vector_type(8)));
typedef float f32x4 __attribute__((ext_vector_type(4)));

#define NT 512   // timesteps
#define NB 128   // batch
#define NI 256   // input dim
#define NH 512   // hidden dim

// ---------------------------------------------------------------------------
// W (fp32 [N][K]) -> fragment-linear f16 for MFMA B-operand.
// Block b = t_n*KT + t_k; lane l holds 8 elems: n = t_n*16 + (l&15),
// k = t_k*32 + (l>>4)*8 + j. Also zeroes the 8 groups x 32 packed wave-flags
// (ws is re-poisoned each launch). Grid 196*256 = 50176 >= 49408.
// ---------------------------------------------------------------------------
__global__ void w_transform(const float* __restrict__ Whh,
                            const float* __restrict__ Win,
                            _Float16* __restrict__ Wf_hh,
                            _Float16* __restrict__ Wf_in,
                            int* __restrict__ flags) {
  int tid = blockIdx.x * blockDim.x + threadIdx.x;
  if (tid < 32768) {                    // W_hh: 32 n-tiles * 16 k-tiles
    int l = tid & 63, b = tid >> 6;
    int tk = b & 15, tn = b >> 4;
    int n = tn * 16 + (l & 15);
    int k = tk * 32 + (l >> 4) * 8;
    const float* src = Whh + (size_t)n * NH + k;
    _Float16* dst = Wf_hh + (size_t)tid * 8;
#pragma unroll
    for (int j = 0; j < 8; ++j) dst[j] = (_Float16)src[j];
  } else if (tid < 32768 + 16384) {     // W_in: 32 n-tiles * 8 k-tiles
    int t2 = tid - 32768;
    int l = t2 & 63, b = t2 >> 6;
    int tk = b & 7, tn = b >> 3;
    int n = tn * 16 + (l & 15);
    int k = tk * 32 + (l >> 4) * 8;
    const float* src = Win + (size_t)n * NI + k;
    _Float16* dst = Wf_in + (size_t)t2 * 8;
#pragma unroll
    for (int j = 0; j < 8; ++j) dst[j] = (_Float16)src[j];
  } else if (tid < 32768 + 16384 + 256) {  // 8 groups * 32 packed wave-flags
    flags[tid - 32768 - 16384] = 0;
  }
}

// ---------------------------------------------------------------------------
// Phase 1: xin = x @ W_in^T  (M=65536, K=256, N=512), fp32 out into d_out.
// (unchanged from the passing baseline)
// ---------------------------------------------------------------------------
__global__ __launch_bounds__(256)
void input_proj(const float* __restrict__ x,
                const _Float16* __restrict__ Wf_in,
                float* __restrict__ xin) {
  int lane = threadIdx.x & 63;
  int wv = threadIdx.x >> 6;
  int m0 = blockIdx.x * 16;
  int c = lane & 15, q = lane >> 4;
  int row = m0 + c;

  f32x4 acc[8];
#pragma unroll
  for (int i = 0; i < 8; ++i) acc[i] = (f32x4){0.f, 0.f, 0.f, 0.f};

#pragma unroll
  for (int kc = 0; kc < 8; ++kc) {
    const float4* ap = (const float4*)(x + (size_t)row * NI + kc * 32 + q * 8);
    float4 a0 = ap[0], a1 = ap[1];
    half8 a;
    a[0] = (_Float16)a0.x; a[1] = (_Float16)a0.y;
    a[2] = (_Float16)a0.z; a[3] = (_Float16)a0.w;
    a[4] = (_Float16)a1.x; a[5] = (_Float16)a1.y;
    a[6] = (_Float16)a1.z; a[7] = (_Float16)a1.w;
#pragma unroll
    for (int nt = 0; nt < 8; ++nt) {
      int tn = wv * 8 + nt;
      const half8* bp =
          (const half8*)(Wf_in + (((size_t)(tn * 8 + kc)) * 64 + lane) * 8);
      acc[nt] = __builtin_amdgcn_mfma_f32_16x16x32_f16(a, *bp, acc[nt], 0, 0, 0);
    }
  }
#pragma unroll
  for (int nt = 0; nt < 8; ++nt) {
    int n = wv * 128 + nt * 16 + c;
#pragma unroll
    for (int r = 0; r < 4; ++r) {
      int m = q * 4 + r;
      xin[(size_t)(m0 + m) * NH + n] = acc[nt][r];
    }
  }
}

// ---------------------------------------------------------------------------
// Phase 2: recurrence, 64 wgs = 8 batch-groups x 8 col-slices. Round-0's
// PROVEN memory patterns throughout: row-major f16 hbuf [2][NB][NH], h16s
// bounce for the coalesced exchange store, contiguous 16KB refill + u64 LDS
// transpose, bfrag[16]/wave resident, relaxed agent atomics only.
//
// Sync chain shortened 4 barriers -> 2:
//  * sync(a) [h16s ready; h_sh MFMA reads done]: kept (__syncthreads).
//    Drains ~nothing: all scattered dout stores are issued a full step
//    earlier and long since acked.
//  * sync(b) DELETED: per-WAVE flags. After its one coalesced u64 exchange
//    store, each wave runs inline s_waitcnt vmcnt(0) (only that store is
//    outstanding) and lane0 stores its wave-flag (relaxed agent). Proven
//    in round 6.
//  * dout stores issue AFTER the flag: fire-and-forget, off critical path.
//  * sync(c) DELETED: every wave spins (lanes<32) on the group's 32 PACKED
//    flags (128B = 1-2 lines, coalesced poll) with s_sleep throttle.
//  * sync(d) [h_sh ready]: kept (__syncthreads).
// Slot-reuse safety (unchanged transitive argument): my flag t+2 (stored at
// step t+1) comes after my step-t refill loads completed (their values were
// consumed into LDS before sync(d) at step t); partner rewrites slot t&1 at
// its step t+2 only after observing ALL flags >= t+2.
// ---------------------------------------------------------------------------
__global__ __launch_bounds__(256, 1)
void recurrence(float* __restrict__ dout,          // xin in-place -> h, + final
                const float* __restrict__ h0,
                const _Float16* __restrict__ Wf,   // fragment-linear W_hh
                unsigned long long* __restrict__ hbuf64,  // [2][NB][NH] f16
                int* __restrict__ flags) {
  __shared__ _Float16 h_sh[16][520];   // full h rows (A source), 16B rows
  __shared__ _Float16 h16s[16][72];    // epilogue->exchange bounce (2 KB)

  int g = blockIdx.x >> 3, s = blockIdx.x & 7;
  int tid = threadIdx.x, lane = tid & 63, wv = tid >> 6;  // 4 waves
  int c = lane & 15, q = lane >> 4;
  int m0 = g * 16;                      // batch row base
  int n0 = s * 64;                      // hidden col base
  int ncol = wv * 16 + c;               // local col this thread epilogues

  // resident B-fragments: this wave's 16-col n-tile, all K (64 VGPRs/lane)
  int nt_global = s * 4 + wv;
  half8 bfrag[16];
#pragma unroll
  for (int kc = 0; kc < 16; ++kc)
    bfrag[kc] =
        *(const half8*)(Wf + (((size_t)(nt_global * 16 + kc)) * 64 + lane) * 8);

  // fp32 master state: this thread's 4 rows x 1 col (matches C-fragment)
  float h32r[4];
#pragma unroll
  for (int r = 0; r < 4; ++r)
    h32r[r] = h0[(size_t)(m0 + q * 4 + r) * NH + n0 + ncol];

  // init h_sh from h0
  for (int i = tid; i < 16 * 512; i += 256) {
    int m = i >> 9, n = i & 511;
    h_sh[m][n] = (_Float16)h0[(size_t)(m0 + m) * NH + n];
  }
  __syncthreads();

  int* fbase = flags + g * 32;          // 32 packed wave-flags per group
  int* myflag = fbase + s * 4 + wv;
  unsigned long long* hb64 = (unsigned long long*)hbuf64;

  // copy-out addressing (thread i handles row i>>4, 4-col chunk i&15)
  int cm = tid >> 4, cc = tid & 15;

#pragma unroll 1
  for (int t = 0; t < NT; ++t) {
    // xin: 4 scattered dwords, same thread overwrites them later
    const float* xp = dout + ((size_t)t * NB + m0) * NH + n0;
    float xv[4];
#pragma unroll
    for (int r = 0; r < 4; ++r) xv[r] = xp[(size_t)(q * 4 + r) * NH + ncol];

    // P = h @ Wslice^T, K=512; two acc chains
    f32x4 acc0 = (f32x4){0.f, 0.f, 0.f, 0.f};
    f32x4 acc1 = (f32x4){0.f, 0.f, 0.f, 0.f};
#pragma unroll
    for (int kc = 0; kc < 16; kc += 2) {
      half8 a0 = *(const half8*)&h_sh[c][kc * 32 + q * 8];
      half8 a1 = *(const half8*)&h_sh[c][(kc + 1) * 32 + q * 8];
      acc0 = __builtin_amdgcn_mfma_f32_16x16x32_f16(a0, bfrag[kc], acc0, 0, 0, 0);
      acc1 = __builtin_amdgcn_mfma_f32_16x16x32_f16(a1, bfrag[kc + 1], acc1, 0, 0, 0);
    }

    // epilogue: h_new = relu(0.8 h + 0.2 (xin + P)) -> h16s bounce only
    bool last = (t == NT - 1);
#pragma unroll
    for (int r = 0; r < 4; ++r) {
      int m = q * 4 + r;
      float hn = 0.8f * h32r[r] + 0.2f * (xv[r] + acc0[r] + acc1[r]);
      hn = fmaxf(hn, 0.f);
      h32r[r] = hn;
      h16s[m][ncol] = (_Float16)hn;
    }

    if (last) {
#pragma unroll
      for (int r = 0; r < 4; ++r) {
        int m = q * 4 + r;
        dout[((size_t)t * NB + m0 + m) * NH + n0 + ncol] = h32r[r];
        dout[(size_t)NT * NB * NH + (size_t)(m0 + m) * NH + n0 + ncol] = h32r[r];
      }
      break;
    }

    __syncthreads();  // (a) h16s complete; all h_sh MFMA reads done

    // coalesced exchange store: 256 threads x 8B, 128B-contiguous per row
    __hip_atomic_store(
        hb64 + ((((size_t)(t & 1) * NB + m0 + cm) * NH + n0 + cc * 4) >> 2),
        *(const unsigned long long*)&h16s[cm][cc * 4],
        __ATOMIC_RELAXED, __HIP_MEMORY_SCOPE_AGENT);

    // wave-local drain: only the exchange store is outstanding here
    asm volatile("s_waitcnt vmcnt(0)" ::: "memory");
    if (lane == 0)
      __hip_atomic_store(myflag, t + 1, __ATOMIC_RELAXED,
                         __HIP_MEMORY_SCOPE_AGENT);

    // dout h-stores AFTER the flag: fire-and-forget, acked by next barrier+step
#pragma unroll
    for (int r = 0; r < 4; ++r)
      dout[((size_t)t * NB + m0 + q * 4 + r) * NH + n0 + ncol] = h32r[r];

    // spin: every wave, lanes 0..31 poll the 32 packed flags (1-2 lines)
    if (lane < 32) {
      while (__hip_atomic_load(fbase + lane, __ATOMIC_RELAXED,
                               __HIP_MEMORY_SCOPE_AGENT) < t + 1) {
        __builtin_amdgcn_s_sleep(1);
      }
    }

    // refill h_sh: 16 KB contiguous, 8 u64 loads/thread, then u64 LDS stores
    {
      const unsigned long long* hb =
          hb64 + ((((size_t)(t & 1) * NB + m0) * NH) >> 2);
      unsigned long long v[8];
#pragma unroll
      for (int j = 0; j < 8; ++j) {
        int k = tid + j * 256;          // 0..2047 8B chunks
        v[j] = __hip_atomic_load(hb + k, __ATOMIC_RELAXED,
                                 __HIP_MEMORY_SCOPE_AGENT);
      }
#pragma unroll
      for (int j = 0; j < 8; ++j) {
        int k = tid + j * 256;
        int m = k >> 7, o = k & 127;    // 128 8B-chunks per 512-col row
        *(unsigned long long*)&h_sh[m][o * 4] = v[j];
      }
    }
    __syncthreads();  // (d) h_sh ready for next step
  }
}

// ---------------------------------------------------------------------------
extern "C" void kernel_launch(void* const* d_in, const int* in_sizes, int n_in,
                              void* d_out, int out_size, void* d_ws,
                              size_t ws_size, hipStream_t stream) {
  const float* x      = (const float*)d_in[0];   // [512][128][256]
  const float* hidden = (const float*)d_in[1];   // [128][512]
  const float* W_in   = (const float*)d_in[2];   // [512][256]
  const float* W_hh   = (const float*)d_in[3];   // [512][512]
  float* out = (float*)d_out;

  // ws layout (769KB): Wf_hh 512KB | Wf_in 256KB (aliased by hbuf after
  // input_proj; flag-gated so no zero-init needed) | flags 1KB
  _Float16* Wf_hh = (_Float16*)d_ws;
  _Float16* Wf_in = Wf_hh + (size_t)NH * NH;
  unsigned long long* hbuf = (unsigned long long*)Wf_in;  // alias, stream-ordered
  int* flags = (int*)((char*)d_ws + (size_t)NH * NH * 2 + (size_t)NH * NI * 2);

  w_transform<<<196, 256, 0, stream>>>(W_hh, W_in, Wf_hh, Wf_in, flags);
  input_proj<<<(NT * NB) / 16, 256, 0, stream>>>(x, Wf_in, out);

  void* args[] = {(void*)&out, (void*)&hidden, (void*)&Wf_hh, (void*)&hbuf,
                  (void*)&flags};
  hipLaunchCooperativeKernel((void*)recurrence, dim3(64), dim3(256), args, 0,
                             stream);
}

// Round 8
// 1360.692 us; speedup vs baseline: 1.9521x; 1.3284x over previous
//
#include <hip/hip_runtime.h>

typedef _Float16 half8 __attribute__((ext_vector_type(8)));
typedef float f32x4 __attribute__((ext_vector_type(4)));

#define NT 512   // timesteps
#define NB 128   // batch
#define NI 256   // input dim
#define NH 512   // hidden dim
#define NG 8     // batch groups (16 rows each)
#define NS 8     // column slices (64 cols each)
#define FLAG_STRIDE 16  // ints -> 64B per flag, avoid line sharing

// ---------------------------------------------------------------------------
// W (fp32 [N][K]) -> fragment-linear f16 for MFMA B-operand.
// Block b = t_n*KT + t_k; lane l holds 8 elems: n = t_n*16 + (l&15),
// k = t_k*32 + (l>>4)*8 + j. Also zeroes the barrier flags (ws is poisoned).
// ---------------------------------------------------------------------------
__global__ void w_transform(const float* __restrict__ Whh,
                            const float* __restrict__ Win,
                            _Float16* __restrict__ Wf_hh,
                            _Float16* __restrict__ Wf_in,
                            int* __restrict__ flags) {
  int tid = blockIdx.x * blockDim.x + threadIdx.x;
  if (tid < 32768) {                    // W_hh: 32 n-tiles * 16 k-tiles
    int l = tid & 63, b = tid >> 6;
    int tk = b & 15, tn = b >> 4;
    int n = tn * 16 + (l & 15);
    int k = tk * 32 + (l >> 4) * 8;
    const float* src = Whh + (size_t)n * NH + k;
    _Float16* dst = Wf_hh + (size_t)tid * 8;
#pragma unroll
    for (int j = 0; j < 8; ++j) dst[j] = (_Float16)src[j];
  } else if (tid < 32768 + 16384) {     // W_in: 32 n-tiles * 8 k-tiles
    int t2 = tid - 32768;
    int l = t2 & 63, b = t2 >> 6;
    int tk = b & 7, tn = b >> 3;
    int n = tn * 16 + (l & 15);
    int k = tk * 32 + (l >> 4) * 8;
    const float* src = Win + (size_t)n * NI + k;
    _Float16* dst = Wf_in + (size_t)t2 * 8;
#pragma unroll
    for (int j = 0; j < 8; ++j) dst[j] = (_Float16)src[j];
  } else if (tid < 32768 + 16384 + NG * NS * FLAG_STRIDE) {
    flags[tid - 32768 - 16384] = 0;
  }
}

// ---------------------------------------------------------------------------
// Phase 1: xin = x @ W_in^T  (M=65536, K=256, N=512), fp32 out into d_out.
// ---------------------------------------------------------------------------
__global__ __launch_bounds__(256)
void input_proj(const float* __restrict__ x,
                const _Float16* __restrict__ Wf_in,
                float* __restrict__ xin) {
  int lane = threadIdx.x & 63;
  int wv = threadIdx.x >> 6;
  int m0 = blockIdx.x * 16;
  int c = lane & 15, q = lane >> 4;
  int row = m0 + c;

  f32x4 acc[8];
#pragma unroll
  for (int i = 0; i < 8; ++i) acc[i] = (f32x4){0.f, 0.f, 0.f, 0.f};

#pragma unroll
  for (int kc = 0; kc < 8; ++kc) {
    const float4* ap = (const float4*)(x + (size_t)row * NI + kc * 32 + q * 8);
    float4 a0 = ap[0], a1 = ap[1];
    half8 a;
    a[0] = (_Float16)a0.x; a[1] = (_Float16)a0.y;
    a[2] = (_Float16)a0.z; a[3] = (_Float16)a0.w;
    a[4] = (_Float16)a1.x; a[5] = (_Float16)a1.y;
    a[6] = (_Float16)a1.z; a[7] = (_Float16)a1.w;
#pragma unroll
    for (int nt = 0; nt < 8; ++nt) {
      int tn = wv * 8 + nt;
      const half8* bp =
          (const half8*)(Wf_in + (((size_t)(tn * 8 + kc)) * 64 + lane) * 8);
      acc[nt] = __builtin_amdgcn_mfma_f32_16x16x32_f16(a, *bp, acc[nt], 0, 0, 0);
    }
  }
#pragma unroll
  for (int nt = 0; nt < 8; ++nt) {
    int n = wv * 128 + nt * 16 + c;
#pragma unroll
    for (int r = 0; r < 4; ++r) {
      int m = q * 4 + r;
      xin[(size_t)(m0 + m) * NH + n] = acc[nt][r];
    }
  }
}

// ---------------------------------------------------------------------------
// Phase 2: recurrence, 64 wgs = 8 batch-groups x 8 col-slices. EXACT round-0
// (proven 1069us) structure and protocol, with ONE change: the scattered
// dout[t] h-stores (4 dwords/thread, 2KB stride -> 1024 partial-line acks
// per block) are DEFERRED to the top of step t+1. In round-0 they issued in
// the epilogue immediately before sync(a), whose compiler-emitted
// s_waitcnt vmcnt(0) drain awaited all their LLC write-merge acks with zero
// absorption window -- putting them on the per-step critical chain. Issued
// at step start instead, they fly during the whole MFMA+epilogue phase
// (~800cy) before any barrier drain touches them. vmcnt retires in issue
// order, so the epilogue's wait for the xv loads (issued first) does not
// wait for these store acks. No other thread ever touches dout[t-1,(m,ncol)],
// and h32r still holds h[t-1] at step-t start (it IS the master state).
// ---------------------------------------------------------------------------
__global__ __launch_bounds__(256, 1)
void recurrence(float* __restrict__ dout,          // xin in-place -> h, + final
                const float* __restrict__ h0,
                const _Float16* __restrict__ Wf,   // fragment-linear W_hh
                _Float16* __restrict__ hbuf,       // [2][NB][NH] f16 exchange
                int* __restrict__ flags) {
  __shared__ _Float16 h_sh[16][520];   // full h rows (A source), 16B-aligned rows
  __shared__ _Float16 h16s[16][72];    // epilogue->exchange bounce (2 KB)

  int g = blockIdx.x >> 3, s = blockIdx.x & 7;
  int tid = threadIdx.x, lane = tid & 63, wv = tid >> 6;  // 4 waves
  int c = lane & 15, q = lane >> 4;
  int m0 = g * 16;                      // batch row base
  int n0 = s * 64;                      // hidden col base
  int ncol = wv * 16 + c;               // local col this thread epilogues

  // resident B-fragments: this wave's 16-col n-tile, all K (64 VGPRs/lane)
  int nt_global = s * 4 + wv;
  half8 bfrag[16];
#pragma unroll
  for (int kc = 0; kc < 16; ++kc)
    bfrag[kc] =
        *(const half8*)(Wf + (((size_t)(nt_global * 16 + kc)) * 64 + lane) * 8);

  // fp32 master state: this thread's 4 rows x 1 col (matches C-fragment)
  float h32r[4];
#pragma unroll
  for (int r = 0; r < 4; ++r)
    h32r[r] = h0[(size_t)(m0 + q * 4 + r) * NH + n0 + ncol];

  // init h_sh from h0
  for (int i = tid; i < 16 * 512; i += 256) {
    int m = i >> 9, n = i & 511;
    h_sh[m][n] = (_Float16)h0[(size_t)(m0 + m) * NH + n];
  }
  __syncthreads();

  int* fbase = flags + g * NS * FLAG_STRIDE;
  unsigned long long* hb64 = (unsigned long long*)hbuf;

  // copy-out addressing (thread i handles row i>>4, 4-col chunk i&15)
  int cm = tid >> 4, cc = tid & 15;

#pragma unroll 1
  for (int t = 0; t < NT; ++t) {
    // xin: 4 scattered dwords, same thread overwrites them next step
    const float* xp = dout + ((size_t)t * NB + m0) * NH + n0;
    float xv[4];
#pragma unroll
    for (int r = 0; r < 4; ++r) xv[r] = xp[(size_t)(q * 4 + r) * NH + ncol];

    // DEFERRED dout h-stores of step t-1: fire-and-forget; their acks get
    // the full MFMA+epilogue window before the next barrier drain.
    if (t > 0) {
#pragma unroll
      for (int r = 0; r < 4; ++r)
        dout[((size_t)(t - 1) * NB + m0 + q * 4 + r) * NH + n0 + ncol] =
            h32r[r];
    }

    // P = h @ Wslice^T, K=512; two acc chains
    f32x4 acc0 = (f32x4){0.f, 0.f, 0.f, 0.f};
    f32x4 acc1 = (f32x4){0.f, 0.f, 0.f, 0.f};
#pragma unroll
    for (int kc = 0; kc < 16; kc += 2) {
      half8 a0 = *(const half8*)&h_sh[c][kc * 32 + q * 8];
      half8 a1 = *(const half8*)&h_sh[c][(kc + 1) * 32 + q * 8];
      acc0 = __builtin_amdgcn_mfma_f32_16x16x32_f16(a0, bfrag[kc], acc0, 0, 0, 0);
      acc1 = __builtin_amdgcn_mfma_f32_16x16x32_f16(a1, bfrag[kc + 1], acc1, 0, 0, 0);
    }

    // epilogue: h_new = relu(0.8 h + 0.2 (xin + P))
#pragma unroll
    for (int r = 0; r < 4; ++r) {
      int m = q * 4 + r;
      float hn = 0.8f * h32r[r] + 0.2f * (xv[r] + acc0[r] + acc1[r]);
      hn = fmaxf(hn, 0.f);
      h32r[r] = hn;
      h16s[m][ncol] = (_Float16)hn;
      if (t == NT - 1) {
        dout[((size_t)t * NB + m0 + m) * NH + n0 + ncol] = hn;
        dout[(size_t)NT * NB * NH + (size_t)(m0 + m) * NH + n0 + ncol] = hn;
      }
    }
    if (t == NT - 1) break;

    __syncthreads();  // (a) h16s complete; also all h_sh MFMA reads done

    // coalesced exchange store: 256 threads x 8B, 128B-contiguous per row
    {
      unsigned long long v = *(const unsigned long long*)&h16s[cm][cc * 4];
      __hip_atomic_store(
          hb64 + ((((size_t)(t & 1) * NB + m0 + cm) * NH + n0 + cc * 4) >> 2),
          v, __ATOMIC_RELAXED, __HIP_MEMORY_SCOPE_AGENT);
    }
    __syncthreads();  // (b) barrier drains vmcnt(0): stores are LLC-visible

    if (tid == 0)
      __hip_atomic_store(&fbase[s * FLAG_STRIDE], t + 1, __ATOMIC_RELAXED,
                         __HIP_MEMORY_SCOPE_AGENT);
    if (wv == 0 && lane < NS) {
      while (__hip_atomic_load(&fbase[lane * FLAG_STRIDE], __ATOMIC_RELAXED,
                               __HIP_MEMORY_SCOPE_AGENT) < t + 1) {
      }
    }
    __syncthreads();  // (c) all slices published step t+1

    // refill h_sh: 16 KB, 8 independent 8B sc1 loads/thread, then LDS stores
    {
      const unsigned long long* hb =
          hb64 + ((((size_t)(t & 1) * NB + m0) * NH) >> 2);
      unsigned long long v[8];
#pragma unroll
      for (int j = 0; j < 8; ++j) {
        int k = tid + j * 256;          // 0..2047 8B chunks
        v[j] = __hip_atomic_load(hb + k, __ATOMIC_RELAXED,
                                 __HIP_MEMORY_SCOPE_AGENT);
      }
#pragma unroll
      for (int j = 0; j < 8; ++j) {
        int k = tid + j * 256;
        int m = k >> 7, o = k & 127;    // 128 8B-chunks per 512-col row
        *(unsigned long long*)&h_sh[m][o * 4] = v[j];
      }
    }
    __syncthreads();  // (d) h_sh ready for next step
  }
}

// ---------------------------------------------------------------------------
extern "C" void kernel_launch(void* const* d_in, const int* in_sizes, int n_in,
                              void* d_out, int out_size, void* d_ws,
                              size_t ws_size, hipStream_t stream) {
  const float* x      = (const float*)d_in[0];   // [512][128][256]
  const float* hidden = (const float*)d_in[1];   // [128][512]
  const float* W_in   = (const float*)d_in[2];   // [512][256]
  const float* W_hh   = (const float*)d_in[3];   // [512][512]
  float* out = (float*)d_out;

  // ws layout: Wf_hh 512KB | Wf_in 256KB (aliased by hbuf after input_proj) |
  //            flags 4KB
  _Float16* Wf_hh = (_Float16*)d_ws;
  _Float16* Wf_in = Wf_hh + (size_t)NH * NH;
  _Float16* hbuf  = Wf_in;                        // alias: safe, stream-ordered
  int* flags = (int*)((char*)d_ws + (size_t)NH * NH * 2 + (size_t)NH * NI * 2);

  w_transform<<<196, 256, 0, stream>>>(W_hh, W_in, Wf_hh, Wf_in, flags);
  input_proj<<<(NT * NB) / 16, 256, 0, stream>>>(x, Wf_in, out);

  void* args[] = {(void*)&out, (void*)&hidden, (void*)&Wf_hh, (void*)&hbuf,
                  (void*)&flags};
  hipLaunchCooperativeKernel((void*)recurrence, dim3(NG * NS), dim3(256), args,
                             0, stream);
}